// Round 4
// baseline (543.810 us; speedup 1.0000x reference)
//
#include <hip/hip_runtime.h>

// AdaConv2d as pre-pass + implicit GEMM (bf16 MFMA 16x16x32, fp32 acc).
//
// Main (v5): barrier-free K-loop.
//   - A (pixels): 64-pix tile spans 2 x-rows -> 9 taps live in 4 padded xp rows.
//     One ic-half panel (232 x 64 = 29.7 KB) in LDS, XOR-swizzled (proven v3/v4).
//     Restaged once mid-kernel (half boundary) with vmcnt(0) + double barrier.
//   - B (weights): DIRECT global->register, 3 register sets, load-after-use
//     (~2 chunk-times of L2 latency cover). wq is L2-resident under the XCD
//     swizzle (round-3: FETCH 42 MB). No per-chunk barriers at all.
//   - Occupancy: LDS 29.7 KB, VGPR-limited ~3 blocks/CU = 12 free-running waves.

typedef __bf16 v8bf __attribute__((ext_vector_type(8)));
typedef float  v4f  __attribute__((ext_vector_type(4)));
typedef unsigned short v8us __attribute__((ext_vector_type(8)));

#define IC_  128
#define OC_  256
#define HH   56
#define WW_  56
#define HW_  3136
#define PW   58                      // padded spatial dim
#define XP_PER_B (PW * PW * IC_)     // 430592 elems
#define WQ_ELEMS (4 * 9 * OC_ * IC_) // 1179648 elems

__device__ __forceinline__ unsigned short f2bf(float f) {
    unsigned u = __builtin_bit_cast(unsigned, f);
    u += 0x7fffu + ((u >> 16) & 1u);    // RNE
    return (unsigned short)(u >> 16);
}

typedef __attribute__((address_space(3))) unsigned int lds_u32_t;
typedef const __attribute__((address_space(1))) unsigned int gbl_u32_t;

__device__ __forceinline__ void gload_lds16(const unsigned short* gsrc, unsigned short* ldst) {
    // dest = (wave-uniform ldst) + lane*16B; per-lane gsrc; 16B per lane.
    __builtin_amdgcn_global_load_lds((gbl_u32_t*)gsrc,
                                     (lds_u32_t*)(unsigned int)(unsigned long long)(uintptr_t)ldst,
                                     16, 0, 0);
}

// ---- pre-pass 1: x[b][ic][h][w] fp32 -> xp[b][h+1][w+1][ic] bf16, plus border zeroing ----
__global__ __launch_bounds__(256)
void transpose_pad(const float* __restrict__ x, unsigned short* __restrict__ xp)
{
    __shared__ unsigned short lt[IC_ * 58];   // [ic][w], stride 58
    const int blk = blockIdx.x;               // b*56 + h
    const int b = blk / HH, h = blk % HH;
    const int t = threadIdx.x;
    const float* xb = x + (size_t)b * IC_ * HW_ + h * WW_;
    #pragma unroll
    for (int i = 0; i < 7; ++i) {
        int e4 = t + i * 256;                 // < 1792
        int ic = e4 / 14;
        int w4 = (e4 - ic * 14) * 4;
        v4f v = *(const v4f*)&xb[ic * HW_ + w4];
        unsigned lo = (unsigned)f2bf(v[0]) | ((unsigned)f2bf(v[1]) << 16);
        unsigned hi = (unsigned)f2bf(v[2]) | ((unsigned)f2bf(v[3]) << 16);
        unsigned* dst = (unsigned*)&lt[ic * 58 + w4];
        dst[0] = lo;
        dst[1] = hi;
    }
    __syncthreads();
    unsigned short* xpb = xp + (size_t)b * XP_PER_B + (size_t)(h + 1) * PW * IC_;
    #pragma unroll
    for (int i = 0; i < 4; ++i) {
        int s = t + i * 256;
        if (s < 896) {                        // 56 w * 16 ic-groups
            int w = s >> 4, icg = s & 15;
            unsigned short v[8];
            #pragma unroll
            for (int j = 0; j < 8; ++j) v[j] = lt[(icg * 8 + j) * 58 + w];
            *(v8us*)&xpb[(w + 1) * IC_ + icg * 8] = *(const v8us*)v;
        }
    }
    if (t < 32) {
        int col = (t >> 4) * 57;              // 0 or 57
        *(v8us*)&xpb[(size_t)col * IC_ + (t & 15) * 8] = (v8us)(unsigned short)0;
    }
    if (h == 0 || h == HH - 1) {
        unsigned short* row = xp + (size_t)b * XP_PER_B + (h == 0 ? 0 : (size_t)(PW - 1) * PW * IC_);
        for (int s = t; s < 928; s += 256)
            *(v8us*)&row[(size_t)s * 8] = (v8us)(unsigned short)0;
    }
}

// ---- pre-pass 2: wq[d][r][oc][ic] = bf16(kbase[oc][ic][r] * kmask[d][ic][r]) ----
__global__ __launch_bounds__(256)
void build_weights(const float* __restrict__ kbase, const float* __restrict__ kmask,
                   unsigned short* __restrict__ wq)
{
    int t  = blockIdx.x * 256 + threadIdx.x;   // < 1179648
    int ic = t & 127;
    int oc = (t >> 7) & 255;
    int rd = t >> 15;                          // d*9 + r
    int r  = rd % 9, d = rd / 9;
    float v = kbase[oc * 1152 + ic * 9 + r] * kmask[d * 1152 + ic * 9 + r];
    wq[t] = f2bf(v);
}

// ---- main: implicit GEMM, A panel in LDS, B in registers (3-deep), barrier-free K-loop ----
__global__ __launch_bounds__(256, 3)
void adaconv_main(const unsigned short* __restrict__ xp,
                  const unsigned short* __restrict__ wq,
                  const int* __restrict__ demog,
                  float* __restrict__ out)
{
    __shared__ unsigned short panel[232 * 64];   // A ic-half panel, 29,696 B, swizzled

    const int t    = threadIdx.x;
    const int lane = t & 63;
    const int quad = lane >> 4;
    const int l15  = lane & 15;
    const int wid  = __builtin_amdgcn_readfirstlane(t >> 6);   // 0..3, oc quarter

    // bijective XCD-aware remap: 3136 blocks = 8 XCDs x 392; contiguous b-runs per XCD
    const int lin = blockIdx.y * 49 + blockIdx.x;
    const int nl  = (lin & 7) * 392 + (lin >> 3);
    const int mtile = nl % 49;
    const int b     = nl / 49;

    const int p0 = mtile * 64;
    const int d  = demog[b];
    const int h0 = p0 / WW_;          // tile spans x-rows h0, h0+1 (always exactly 2)

    // A fragment row bases: frag mi, pix = p0 + mi*16 + l15; R in [0,232)
    int baseR[4];
    #pragma unroll
    for (int mi = 0; mi < 4; ++mi) {
        int pix = p0 + mi * 16 + l15;
        int hh  = pix / WW_;
        int wwp = pix - hh * WW_;
        baseR[mi] = (hh - h0 + 1) * PW + (wwp + 1);
    }

    // A staging: lane l fills LDS slot (R = k*8 + (l>>3), slot = l&7); content = global
    // slot (l&7)^(l>>3) of row R (inverse swizzle; proven in v3/v4).
    const int olane = ((lane >> 3) << 7) + (((lane & 7) ^ (lane >> 3)) << 3);  // elems
    const unsigned short* xpb = xp + (size_t)b * XP_PER_B + (size_t)h0 * PW * IC_;

    // B per-lane fragment pointers: oc = wid*64 + ni*16 + l15, k-slot = quad*8
    const unsigned short* bbase[4];
    #pragma unroll
    for (int ni = 0; ni < 4; ++ni)
        bbase[ni] = wq + (size_t)d * 9 * OC_ * IC_
                  + (size_t)(wid * 64 + ni * 16 + l15) * IC_ + quad * 8;

    v4f acc[4][4];
    #pragma unroll
    for (int mi = 0; mi < 4; ++mi)
        #pragma unroll
        for (int ni = 0; ni < 4; ++ni)
            acc[mi][ni] = (v4f)0.0f;

    int tA[4];
    v8us bu[3][4];

    // chunk cc in [0,36): half = cc/18, cl = cc%18, r = cl>>1, il = cl&1,
    // ic0 = half*64 + il*32.
    #define STAGEA(half_) do {                                                  \
        const unsigned short* xph_ = xpb + (half_) * 64;                        \
        _Pragma("unroll")                                                       \
        for (int kk = 0; kk < 8; ++kk) {                                        \
            int k_ = wid + kk * 4;                                              \
            if (k_ < 29) gload_lds16(xph_ + k_ * 1024 + olane, panel + k_ * 512); \
        } } while (0)

    #define LOADB(slot_, cc_) do {                                              \
        const int cl_  = (cc_) % 18;                                            \
        const int off_ = (cl_ >> 1) * (OC_ * IC_) + ((cc_) / 18) * 64 + (cl_ & 1) * 32; \
        _Pragma("unroll")                                                       \
        for (int ni = 0; ni < 4; ++ni)                                          \
            bu[slot_][ni] = *(const v8us*)(bbase[ni] + off_);                   \
        } while (0)

    #define SETTAP(r_) do {                                                     \
        const int offR_ = ((r_) / 3 - 1) * PW + ((r_) % 3 - 1);                 \
        _Pragma("unroll")                                                       \
        for (int mi = 0; mi < 4; ++mi) {                                        \
            int R_ = baseR[mi] + offR_;                                         \
            tA[mi] = (R_ << 7) + (((R_ & 7) ^ quad) << 4);                      \
        } } while (0)

    // prologue: A half-0, then B chunks 0..2 (12 loads). Fence keeps issue order
    // (A gload_lds first) so vmcnt(12) == "all my A loads landed".
    STAGEA(0);
    asm volatile("" ::: "memory");
    LOADB(0, 0);
    LOADB(1, 1);
    LOADB(2, 2);
    asm volatile("s_waitcnt vmcnt(12)" ::: "memory");
    __builtin_amdgcn_s_barrier();

    #pragma unroll
    for (int c = 0; c < 36; ++c) {
        if (c == 18) {
            // half boundary: all waves done reading half-0 (frag data already in
            // regs before each wave's chunk-17 MFMAs issued), restage, drain, resync.
            __builtin_amdgcn_s_barrier();
            STAGEA(1);
            asm volatile("s_waitcnt vmcnt(0)" ::: "memory");
            __builtin_amdgcn_s_barrier();
        }
        const int cl = c % 18;
        const int r  = cl >> 1;
        const int il = cl & 1;
        if (il == 0) SETTAP(r);

        v8us au[4];
        #pragma unroll
        for (int mi = 0; mi < 4; ++mi)
            au[mi] = *(const v8us*)((const char*)panel + (tA[mi] ^ (il << 6)));

        // B(c) must be landed; B(c+1), B(c+2) may stay in flight.
        asm volatile("s_waitcnt vmcnt(8)" ::: "memory");

        __builtin_amdgcn_s_setprio(1);
        #pragma unroll
        for (int mi = 0; mi < 4; ++mi) {
            v8bf a = __builtin_bit_cast(v8bf, au[mi]);
            #pragma unroll
            for (int ni = 0; ni < 4; ++ni) {
                v8bf bb = __builtin_bit_cast(v8bf, bu[c % 3][ni]);
                acc[mi][ni] = __builtin_amdgcn_mfma_f32_16x16x32_bf16(a, bb, acc[mi][ni], 0, 0, 0);
            }
        }
        __builtin_amdgcn_s_setprio(0);

        // refill the just-consumed register set with B(c+3): ~2 chunk-times to land.
        if (c + 3 < 36) LOADB(c % 3, c + 3);
    }
    #undef STAGEA
    #undef LOADB
    #undef SETTAP

    // epilogue: D row = quad*4+reg (pix), col = l15 (oc)
    float* ob = out + ((size_t)b * OC_ + wid * 64) * HW_ + p0;
    #pragma unroll
    for (int ni = 0; ni < 4; ++ni) {
        #pragma unroll
        for (int mi = 0; mi < 4; ++mi) {
            float* o = ob + (size_t)(ni * 16 + l15) * HW_ + mi * 16 + quad * 4;
            *(v4f*)o = acc[mi][ni];
        }
    }
}

extern "C" void kernel_launch(void* const* d_in, const int* in_sizes, int n_in,
                              void* d_out, int out_size, void* d_ws, size_t ws_size,
                              hipStream_t stream) {
    const float* x     = (const float*)d_in[0];
    const int*   demog = (const int*)d_in[1];
    const float* kbase = (const float*)d_in[2];
    const float* kmask = (const float*)d_in[3];
    float* out = (float*)d_out;

    unsigned short* xp = (unsigned short*)d_ws;
    unsigned short* wq = xp + (size_t)64 * XP_PER_B;
    transpose_pad<<<64 * HH, 256, 0, stream>>>(x, xp);
    build_weights<<<WQ_ELEMS / 256, 256, 0, stream>>>(kbase, kmask, wq);
    adaconv_main<<<dim3(49, 64), 256, 0, stream>>>(xp, wq, demog, out);
}

// Round 5
// 417.309 us; speedup vs baseline: 1.3031x; 1.3031x over previous
//
#include <hip/hip_runtime.h>

// AdaConv2d as pre-pass + implicit GEMM (bf16 MFMA 16x16x32, fp32 acc).
//
// Main (v6): barrier-free K-loop with WAVE-PRIVATE B staging.
//   - A (pixels): 64-pix tile spans 2 x-rows -> 9 taps in 4 padded xp rows.
//     One ic-half panel (232 x 64 = 29.7 KB) in LDS, XOR-swizzled (proven v3/v4).
//     Restaged once (half boundary): the ONLY barriers in the kernel (3 total).
//   - B (weights): global_load_lds into 3 x 16 KB buffers (v4's proven L2-friendly
//     path, 42 MB FETCH), but each wave stages ITS OWN oc-quarter -> B sync is
//     purely intra-wave (own vmcnt), no per-chunk barrier.
//   - 1-chunk register prefetch of A and B fragments: ds_reads for chunk c+1 issue
//     during chunk c's MFMA cluster -> LDS latency hidden. Waves free-run.
//   - T5 setprio around MFMA; bijective XCD block swizzle (proven round 3).

typedef __bf16 v8bf __attribute__((ext_vector_type(8)));
typedef float  v4f  __attribute__((ext_vector_type(4)));
typedef unsigned short v8us __attribute__((ext_vector_type(8)));

#define IC_  128
#define OC_  256
#define HH   56
#define WW_  56
#define HW_  3136
#define PW   58                      // padded spatial dim
#define XP_PER_B (PW * PW * IC_)     // 430592 elems
#define WQ_ELEMS (4 * 9 * OC_ * IC_) // 1179648 elems

__device__ __forceinline__ unsigned short f2bf(float f) {
    unsigned u = __builtin_bit_cast(unsigned, f);
    u += 0x7fffu + ((u >> 16) & 1u);    // RNE
    return (unsigned short)(u >> 16);
}

typedef __attribute__((address_space(3))) unsigned int lds_u32_t;
typedef const __attribute__((address_space(1))) unsigned int gbl_u32_t;

__device__ __forceinline__ void gload_lds16(const unsigned short* gsrc, unsigned short* ldst) {
    // dest = (wave-uniform ldst) + lane*16B; per-lane gsrc; 16B per lane.
    __builtin_amdgcn_global_load_lds((gbl_u32_t*)gsrc,
                                     (lds_u32_t*)(unsigned int)(unsigned long long)(uintptr_t)ldst,
                                     16, 0, 0);
}

// ---- pre-pass 1: x[b][ic][h][w] fp32 -> xp[b][h+1][w+1][ic] bf16, plus border zeroing ----
__global__ __launch_bounds__(256)
void transpose_pad(const float* __restrict__ x, unsigned short* __restrict__ xp)
{
    __shared__ unsigned short lt[IC_ * 58];   // [ic][w], stride 58
    const int blk = blockIdx.x;               // b*56 + h
    const int b = blk / HH, h = blk % HH;
    const int t = threadIdx.x;
    const float* xb = x + (size_t)b * IC_ * HW_ + h * WW_;
    #pragma unroll
    for (int i = 0; i < 7; ++i) {
        int e4 = t + i * 256;                 // < 1792
        int ic = e4 / 14;
        int w4 = (e4 - ic * 14) * 4;
        v4f v = *(const v4f*)&xb[ic * HW_ + w4];
        unsigned lo = (unsigned)f2bf(v[0]) | ((unsigned)f2bf(v[1]) << 16);
        unsigned hi = (unsigned)f2bf(v[2]) | ((unsigned)f2bf(v[3]) << 16);
        unsigned* dst = (unsigned*)&lt[ic * 58 + w4];
        dst[0] = lo;
        dst[1] = hi;
    }
    __syncthreads();
    unsigned short* xpb = xp + (size_t)b * XP_PER_B + (size_t)(h + 1) * PW * IC_;
    #pragma unroll
    for (int i = 0; i < 4; ++i) {
        int s = t + i * 256;
        if (s < 896) {                        // 56 w * 16 ic-groups
            int w = s >> 4, icg = s & 15;
            unsigned short v[8];
            #pragma unroll
            for (int j = 0; j < 8; ++j) v[j] = lt[(icg * 8 + j) * 58 + w];
            *(v8us*)&xpb[(w + 1) * IC_ + icg * 8] = *(const v8us*)v;
        }
    }
    if (t < 32) {
        int col = (t >> 4) * 57;              // 0 or 57
        *(v8us*)&xpb[(size_t)col * IC_ + (t & 15) * 8] = (v8us)(unsigned short)0;
    }
    if (h == 0 || h == HH - 1) {
        unsigned short* row = xp + (size_t)b * XP_PER_B + (h == 0 ? 0 : (size_t)(PW - 1) * PW * IC_);
        for (int s = t; s < 928; s += 256)
            *(v8us*)&row[(size_t)s * 8] = (v8us)(unsigned short)0;
    }
}

// ---- pre-pass 2: wq[d][r][oc][ic] = bf16(kbase[oc][ic][r] * kmask[d][ic][r]) ----
__global__ __launch_bounds__(256)
void build_weights(const float* __restrict__ kbase, const float* __restrict__ kmask,
                   unsigned short* __restrict__ wq)
{
    int t  = blockIdx.x * 256 + threadIdx.x;   // < 1179648
    int ic = t & 127;
    int oc = (t >> 7) & 255;
    int rd = t >> 15;                          // d*9 + r
    int r  = rd % 9, d = rd / 9;
    float v = kbase[oc * 1152 + ic * 9 + r] * kmask[d * 1152 + ic * 9 + r];
    wq[t] = f2bf(v);
}

// ---- main: implicit GEMM, wave-private B staging, barrier-free K-loop ----
__global__ __launch_bounds__(256, 2)
void adaconv_main(const unsigned short* __restrict__ xp,
                  const unsigned short* __restrict__ wq,
                  const int* __restrict__ demog,
                  float* __restrict__ out)
{
    __shared__ unsigned short panel[232 * 64];     // A ic-half panel, 29,696 B, swizzled
    __shared__ unsigned short bbuf[3][256 * 32];   // B, 3 x 16 KB; wave w owns rows [32w,32w+32)

    const int t    = threadIdx.x;
    const int lane = t & 63;
    const int quad = lane >> 4;
    const int l15  = lane & 15;
    const int wid  = __builtin_amdgcn_readfirstlane(t >> 6);   // 0..3, oc quarter

    // bijective XCD-aware remap: 3136 blocks = 8 XCDs x 392; contiguous runs per XCD
    const int lin = blockIdx.y * 49 + blockIdx.x;
    const int nl  = (lin & 7) * 392 + (lin >> 3);
    const int mtile = nl % 49;
    const int b     = nl / 49;

    const int p0 = mtile * 64;
    const int d  = demog[b];
    const int h0 = p0 / WW_;          // tile spans x-rows h0, h0+1 (always exactly 2)

    // A fragment row bases: frag mi, pix = p0 + mi*16 + l15; R in [0,232)
    int baseR[4];
    #pragma unroll
    for (int mi = 0; mi < 4; ++mi) {
        int pix = p0 + mi * 16 + l15;
        int hh  = pix / WW_;
        int wwp = pix - hh * WW_;
        baseR[mi] = (hh - h0 + 1) * PW + (wwp + 1);
    }

    // A staging: lane l fills LDS slot (R = k*8 + (l>>3), slot = l&7); content = global
    // slot (l&7)^(l>>3) of row R (inverse swizzle; proven v3/v4).
    const int olane = ((lane >> 3) << 7) + (((lane & 7) ^ (lane >> 3)) << 3);  // elems
    const unsigned short* xpb = xp + (size_t)b * XP_PER_B + (size_t)h0 * PW * IC_;

    // B staging (wave-private): wave w, iter j, lane l fills LDS row128 = 32w + 8j + (l>>3),
    // slot = l&7; content = slot' = (l&7)^(l>>3) -> oc = 2*row + (slot'>>2), kslot = slot'&3.
    // oc = 64w + 16j + 2*(l>>3) + (slot'>>2) -- entirely within this wave's oc quarter.
    const int slotp = (lane & 7) ^ (lane >> 3);
    const unsigned short* sB = wq + (size_t)d * 9 * OC_ * IC_
                             + (size_t)(64 * wid + 2 * (lane >> 3) + (slotp >> 2)) * IC_
                             + (slotp & 3) * 8;

    // B read byte offsets: oc = wid*64 + ni*16 + l15, row128 = oc>>1 (in own quarter),
    // slot = ((oc&1)<<2)|quad, swizzled ^ (row128&7).
    int bOff[4];
    #pragma unroll
    for (int ni = 0; ni < 4; ++ni) {
        int oc = wid * 64 + ni * 16 + l15;
        int r128 = oc >> 1;
        bOff[ni] = (r128 << 7) + (((((oc & 1) << 2) | quad) ^ (r128 & 7)) << 4);
    }

    v4f acc[4][4];
    #pragma unroll
    for (int mi = 0; mi < 4; ++mi)
        #pragma unroll
        for (int ni = 0; ni < 4; ++ni)
            acc[mi][ni] = (v4f)0.0f;

    int  tA[4];
    v8us au[2][4], bu[2][4];

    // chunk cc in [0,36): half = cc/18, cl = cc%18, r = cl>>1, il = cl&1.
    #define STAGEA(half_) do {                                                  \
        const unsigned short* xph_ = xpb + (half_) * 64;                        \
        _Pragma("unroll")                                                       \
        for (int kk = 0; kk < 8; ++kk) {                                        \
            int k_ = wid + kk * 4;                                              \
            if (k_ < 29) gload_lds16(xph_ + k_ * 1024 + olane, panel + k_ * 512); \
        } } while (0)

    // 4 gload_lds per wave; dest rows 32*wid + 8j (own quarter of the buffer)
    #define STAGEB(bufi_, cc_) do {                                             \
        const int cl_  = (cc_) % 18;                                            \
        const int off_ = (cl_ >> 1) * (OC_ * IC_) + ((cc_) / 18) * 64 + (cl_ & 1) * 32; \
        _Pragma("unroll")                                                       \
        for (int j = 0; j < 4; ++j)                                             \
            gload_lds16(sB + off_ + j * 16 * IC_, &bbuf[bufi_][wid * 2048 + j * 512]); \
        } while (0)

    #define SETTAP(r_) do {                                                     \
        const int offR_ = ((r_) / 3 - 1) * PW + ((r_) % 3 - 1);                 \
        _Pragma("unroll")                                                       \
        for (int mi = 0; mi < 4; ++mi) {                                        \
            int R_ = baseR[mi] + offR_;                                         \
            tA[mi] = (R_ << 7) + (((R_ & 7) ^ quad) << 4);                      \
        } } while (0)

    #define READA(set_, cc_) do {                                               \
        const int cl_ = (cc_) % 18;                                             \
        if ((cl_ & 1) == 0) SETTAP(cl_ >> 1);                                   \
        _Pragma("unroll")                                                       \
        for (int mi = 0; mi < 4; ++mi)                                          \
            au[set_][mi] = *(const v8us*)((const char*)panel + (tA[mi] ^ ((cl_ & 1) << 6))); \
        } while (0)

    #define READB(set_, cc_) do {                                               \
        _Pragma("unroll")                                                       \
        for (int ni = 0; ni < 4; ++ni)                                          \
            bu[set_][ni] = *(const v8us*)((const char*)bbuf[(cc_) % 3] + bOff[ni]); \
        } while (0)

    #define DOMFMA(set_) do {                                                   \
        __builtin_amdgcn_s_setprio(1);                                          \
        _Pragma("unroll")                                                       \
        for (int mi = 0; mi < 4; ++mi) {                                        \
            v8bf a_ = __builtin_bit_cast(v8bf, au[set_][mi]);                   \
            _Pragma("unroll")                                                   \
            for (int ni = 0; ni < 4; ++ni) {                                    \
                v8bf b_ = __builtin_bit_cast(v8bf, bu[set_][ni]);               \
                acc[mi][ni] = __builtin_amdgcn_mfma_f32_16x16x32_bf16(a_, b_, acc[mi][ni], 0, 0, 0); \
            }                                                                   \
        }                                                                       \
        __builtin_amdgcn_s_setprio(0);                                          \
    } while (0)

    // prologue: A half-0 + B(0), B(1); full drain; cross-wave barrier for panel.
    STAGEA(0);
    asm volatile("" ::: "memory");
    STAGEB(0, 0);
    STAGEB(1, 1);
    asm volatile("s_waitcnt vmcnt(0)" ::: "memory");
    __builtin_amdgcn_s_barrier();
    READA(0, 0);
    READB(0, 0);

    #pragma unroll
    for (int c = 0; c < 36; ++c) {
        DOMFMA(c & 1);
        if (c == 17) {
            // keep B cadence (B(19) -> buf 1), then restage the A panel.
            STAGEB(1, 19);
            __builtin_amdgcn_s_barrier();          // all waves done reading half-0 panel
            STAGEA(1);
            asm volatile("s_waitcnt vmcnt(0)" ::: "memory");
            __builtin_amdgcn_s_barrier();          // all waves' panel writes landed
            READA(0, 18);                          // set 18&1 = 0
            READB(0, 18);                          // buf 0, staged at c=16, drained above
        } else if (c < 35) {
            if (c + 2 < 36) STAGEB((c + 2) % 3, c + 2);
            READA((c + 1) & 1, c + 1);             // panel ds_reads (no sync needed)
            if (c + 2 < 36) asm volatile("s_waitcnt vmcnt(4)" ::: "memory");  // B(c+1) landed
            else            asm volatile("s_waitcnt vmcnt(0)" ::: "memory");
            READB((c + 1) & 1, c + 1);
        }
    }
    #undef STAGEA
    #undef STAGEB
    #undef SETTAP
    #undef READA
    #undef READB
    #undef DOMFMA

    // epilogue: D row = quad*4+reg (pix), col = l15 (oc)
    float* ob = out + ((size_t)b * OC_ + wid * 64) * HW_ + p0;
    #pragma unroll
    for (int ni = 0; ni < 4; ++ni) {
        #pragma unroll
        for (int mi = 0; mi < 4; ++mi) {
            float* o = ob + (size_t)(ni * 16 + l15) * HW_ + mi * 16 + quad * 4;
            *(v4f*)o = acc[mi][ni];
        }
    }
}

extern "C" void kernel_launch(void* const* d_in, const int* in_sizes, int n_in,
                              void* d_out, int out_size, void* d_ws, size_t ws_size,
                              hipStream_t stream) {
    const float* x     = (const float*)d_in[0];
    const int*   demog = (const int*)d_in[1];
    const float* kbase = (const float*)d_in[2];
    const float* kmask = (const float*)d_in[3];
    float* out = (float*)d_out;

    unsigned short* xp = (unsigned short*)d_ws;
    unsigned short* wq = xp + (size_t)64 * XP_PER_B;
    transpose_pad<<<64 * HH, 256, 0, stream>>>(x, xp);
    build_weights<<<WQ_ELEMS / 256, 256, 0, stream>>>(kbase, kmask, wq);
    adaconv_main<<<dim3(49, 64), 256, 0, stream>>>(xp, wq, demog, out);
}